// Round 10
// baseline (883.455 us; speedup 1.0000x reference)
//
#include <hip/hip_runtime.h>
#include <math.h>

#define NN 20000
#define NE 320000
#define ET 32          // edges per tile
#define ST 132         // LDS row stride in floats

typedef float v2f __attribute__((ext_vector_type(2)));
__device__ __forceinline__ v2f fma2(v2f a, v2f b, v2f c){ return __builtin_elementwise_fma(a,b,c); }
__device__ __forceinline__ v2f mk2(float x, float y){ v2f r; r.x=x; r.y=y; return r; }
__device__ __forceinline__ float frelu(float x){ return fmaxf(x, 0.f); }

// ---------------- histograms: degS over send (normalization), cntR over rec (sort) ----------------
__global__ void k_hist(const int* __restrict__ eidx, int* __restrict__ degS,
                       int* __restrict__ cntR, int mode){
  int t = blockIdx.x*256 + threadIdx.x;
  if(t < NE){
    atomicAdd(&degS[eidx[t]], 1);
    if(mode) atomicAdd(&cntR[eidx[NE+t]], 1);
  }
}

// ---------------- exclusive scan of cntR -> cur[N] (single block) ----------------
__global__ __launch_bounds__(256) void k_scan(const int* __restrict__ cntR,
                                              int* __restrict__ cur){
  __shared__ int part[256];
  __shared__ int pre[256];
  const int t = threadIdx.x;
  const int start = t*80, end = min(start+80, NN);
  int sm = 0;
  for(int n=start;n<end;n++) sm += cntR[n];
  part[t] = sm;
  __syncthreads();
  if(t==0){ int r=0; for(int i=0;i<256;i++){ pre[i]=r; r+=part[i]; } }
  __syncthreads();
  int run = pre[t];
  for(int n=start;n<end;n++){ cur[n]=run; run += cntR[n]; }
}

// ---------------- scatter edge ids into rec-sorted order ----------------
__global__ void k_fill(const int* __restrict__ eidx, int* __restrict__ cur,
                       int* __restrict__ eord){
  int e = blockIdx.x*256 + threadIdx.x;
  if(e < NE){
    int r = eidx[NE+e];
    int p = atomicAdd(&cur[r], 1);
    eord[p] = e;
  }
}

// ---------------- per-node precompute: A = s@W1[0:128], B = s@W1[128:256] ----------------
__global__ __launch_bounds__(256) void k_ab(const float* __restrict__ s,
                                            const float* __restrict__ W1,
                                            float* __restrict__ A,
                                            float* __restrict__ B){
  __shared__ float sx[8*128];
  const int nb = blockIdx.x*8;
  for(int i=threadIdx.x; i<8*128; i+=256) sx[i] = s[(size_t)nb*128 + i];
  __syncthreads();
  const int col = threadIdx.x;
  const int j = col & 127;
  const float* w = W1 + (col < 128 ? 0 : 128*128) + j;
  v2f acc[4];
  #pragma unroll
  for(int n=0;n<4;n++) acc[n]=mk2(0.f,0.f);
  for(int k=0;k<128;k++){
    float wv = w[(size_t)k*128];
    v2f wv2 = mk2(wv, wv);
    #pragma unroll
    for(int n=0;n<4;n++){
      v2f x = mk2(sx[(2*n)*128+k], sx[(2*n+1)*128+k]);
      acc[n] = fma2(x, wv2, acc[n]);
    }
  }
  float* dst = (col<128 ? A : B) + (size_t)nb*128 + j;
  #pragma unroll
  for(int n=0;n<4;n++){
    dst[(size_t)(2*n)*128]   = acc[n].x;
    dst[(size_t)(2*n+1)*128] = acc[n].y;
  }
}

// ======================= flat edge kernel: R8 structure + A-prefetch + fewer barriers =======================
// SORTED=1: rec-sorted edges via eord + Ph8 segmented reduce. SORTED=0: per-edge atomics.
// Weights read ROW-MAJOR (coalesced — R7 post-mortem: never transpose these).
// Ph1->Ph2 and Ph6->Ph7 need no __syncthreads: rows are produced/consumed by the same wave
// (DS ops are in-order per wave); pm passes thread-local in registers.
template<int SORTED>
__global__ __launch_bounds__(256) void k_edge(
    const float* __restrict__ v, const int* __restrict__ eidx,
    const float* __restrict__ Wvw, const float* __restrict__ Wvb,
    const float* __restrict__ W1c, const float* __restrict__ b1,
    const float* __restrict__ W2,  const float* __restrict__ b2,
    const float* __restrict__ pW1, const float* __restrict__ pb1,
    const float* __restrict__ pW2, const float* __restrict__ pb2,
    const float* __restrict__ A,   const float* __restrict__ Bn,
    const int* __restrict__ eord,
    float* __restrict__ Magg, float* __restrict__ Pagg)
{
  __shared__ float B0[ET*ST];   // d -> m
  __shared__ float B2[ET*ST];   // h -> q -> pos_m
  __shared__ float sEP[ET*16];  // edge_attr
  __shared__ int sS[ET], sR[ET];
  const int t  = threadIdx.x;
  const int e0 = blockIdx.x * ET;

  if(t<ET){
    int e = SORTED ? eord[e0+t] : (e0+t);
    sS[t]=eidx[e]; sR[t]=eidx[NE+e];
  }
  __syncthreads();

  // Prefetch the 16 random A[send] gathers this thread needs in Ph3 — issued here,
  // consumed ~5 phases later (latency fully hidden). Bn[rec] stays inline (L1-hot rows).
  const int j3 = t&127, eg3 = t>>7;
  float aPre[16];
  #pragma unroll
  for(int ei=0;ei<16;ei++) aPre[ei] = A[(size_t)sS[eg3*16+ei]*128 + j3];

  const int e1 = t>>3, q1 = t&7;   // Ph1/Ph2/Ph6/Ph7 mapping

  // Ph1: d = v[rec] - v[send] -> B0  (row e1 written by this wave's lanes only)
  {
    const float4* vs = (const float4*)(v + (size_t)sS[e1]*128);
    const float4* vr = (const float4*)(v + (size_t)sR[e1]*128);
    #pragma unroll
    for(int i=0;i<4;i++){
      int f = q1 + i*8;
      float4 a = vr[f], b = vs[f];
      *(float4*)(B0 + e1*ST + f*4) = make_float4(a.x-b.x, a.y-b.y, a.z-b.z, a.w-b.w);
    }
  }
  // no barrier: Ph2 reads row e1, written by same wave (in-order DS per wave)

  // Ph2: v_ij = mv_linear(d, Wv) -> REGISTERS (a0 ch q1, a1 ch q1+8); edge_attr -> sEP
  v2f a0[4], a1[4];                // blade pairs (0,1)(2,3)(4,5)(6,7), live through Ph7
  {
    #pragma unroll
    for(int b=0;b<4;b++){ a0[b]=mk2(0.f,0.f); a1[b]=mk2(0.f,0.f); }
    a0[0].x=Wvb[q1]; a1[0].x=Wvb[q1+8];
    const float* dp = B0 + e1*ST;
    #pragma unroll
    for(int c=0;c<16;c++){
      float4 da=*(const float4*)(dp + c*8);
      float4 db=*(const float4*)(dp + c*8 + 4);
      float4 g0=*(const float4*)(Wvw + (q1*16+c)*4);
      float4 g1=*(const float4*)(Wvw + ((q1+8)*16+c)*4);
      a0[0]=fma2(mk2(da.x,da.y), mk2(g0.x,g0.y), a0[0]);
      a0[1]=fma2(mk2(da.z,da.w), mk2(g0.y,g0.y), a0[1]);
      a0[2]=fma2(mk2(db.x,db.y), mk2(g0.z,g0.z), a0[2]);
      a0[3]=fma2(mk2(db.z,db.w), mk2(g0.z,g0.w), a0[3]);
      a1[0]=fma2(mk2(da.x,da.y), mk2(g1.x,g1.y), a1[0]);
      a1[1]=fma2(mk2(da.z,da.w), mk2(g1.y,g1.y), a1[1]);
      a1[2]=fma2(mk2(db.x,db.y), mk2(g1.z,g1.z), a1[2]);
      a1[3]=fma2(mk2(db.z,db.w), mk2(g1.z,g1.w), a1[3]);
    }
    v2f s0=mk2(0.f,0.f), s1=mk2(0.f,0.f);
    #pragma unroll
    for(int b=0;b<4;b++){ s0=fma2(a0[b],a0[b],s0); s1=fma2(a1[b],a1[b],s1); }
    sEP[e1*16+q1]=s0.x+s0.y; sEP[e1*16+q1+8]=s1.x+s1.y;
  }
  __syncthreads();   // sEP is read cross-wave in Ph3

  // Ph3: h = relu(aPre + Bn[rec] + ea@W1c + b1) -> B2  (packed over c pairs)
  {
    const int j = j3, eg = eg3;
    v2f w1c[8];
    #pragma unroll
    for(int c=0;c<8;c++) w1c[c]=mk2(W1c[(size_t)(2*c)*128 + j], W1c[(size_t)(2*c+1)*128 + j]);
    const float bb = b1[j];
    #pragma unroll
    for(int ei=0; ei<16; ei++){
      const int e = eg*16 + ei;
      const float base = aPre[ei] + Bn[(size_t)sR[e]*128 + j] + bb;
      v2f accv = mk2(0.f,0.f);
      const v2f* eap = (const v2f*)(sEP + e*16);
      #pragma unroll
      for(int c=0;c<8;c++) accv = fma2(eap[c], w1c[c], accv);
      B2[e*ST + j] = frelu(base + accv.x + accv.y);
    }
  }
  __syncthreads();

  // Ph4: m = h@W2 + b2 -> B0 (row-major coalesced weights; SORTED=0 also atomic scatter)
  {
    const int jq = t&31, eg = t>>5;
    const int j0 = jq*4;
    float4 bb = *(const float4*)(b2 + j0);
    v2f acc[4][2];
    #pragma unroll
    for(int a=0;a<4;a++){ acc[a][0]=mk2(bb.x,bb.y); acc[a][1]=mk2(bb.z,bb.w); }
    for(int k=0;k<128;k+=4){
      float4 w0=*(const float4*)(W2 + (size_t)(k+0)*128 + j0);
      float4 w1=*(const float4*)(W2 + (size_t)(k+1)*128 + j0);
      float4 w2=*(const float4*)(W2 + (size_t)(k+2)*128 + j0);
      float4 w3=*(const float4*)(W2 + (size_t)(k+3)*128 + j0);
      v2f w0a=mk2(w0.x,w0.y), w0b=mk2(w0.z,w0.w);
      v2f w1a=mk2(w1.x,w1.y), w1b=mk2(w1.z,w1.w);
      v2f w2a=mk2(w2.x,w2.y), w2b=mk2(w2.z,w2.w);
      v2f w3a=mk2(w3.x,w3.y), w3b=mk2(w3.z,w3.w);
      #pragma unroll
      for(int a=0;a<4;a++){
        float4 h4=*(const float4*)(B2 + (eg*4+a)*ST + k);
        v2f hx=mk2(h4.x,h4.x), hy=mk2(h4.y,h4.y), hz=mk2(h4.z,h4.z), hw=mk2(h4.w,h4.w);
        acc[a][0]=fma2(hx,w0a,acc[a][0]); acc[a][1]=fma2(hx,w0b,acc[a][1]);
        acc[a][0]=fma2(hy,w1a,acc[a][0]); acc[a][1]=fma2(hy,w1b,acc[a][1]);
        acc[a][0]=fma2(hz,w2a,acc[a][0]); acc[a][1]=fma2(hz,w2b,acc[a][1]);
        acc[a][0]=fma2(hw,w3a,acc[a][0]); acc[a][1]=fma2(hw,w3b,acc[a][1]);
      }
    }
    #pragma unroll
    for(int a=0;a<4;a++){
      const int e = eg*4+a;
      *(float4*)(B0 + e*ST + j0) = make_float4(acc[a][0].x,acc[a][0].y,acc[a][1].x,acc[a][1].y);
      if(!SORTED){
        float* mg = Magg + (size_t)sR[e]*128 + j0;
        atomicAdd(mg+0, acc[a][0].x); atomicAdd(mg+1, acc[a][0].y);
        atomicAdd(mg+2, acc[a][1].x); atomicAdd(mg+3, acc[a][1].y);
      }
    }
  }
  __syncthreads();

  // Ph5: q = relu(m@pW1 + pb1) -> B2
  {
    const int jq = t&31, eg = t>>5;
    const int j0 = jq*4;
    float4 bb = *(const float4*)(pb1 + j0);
    v2f acc[4][2];
    #pragma unroll
    for(int a=0;a<4;a++){ acc[a][0]=mk2(bb.x,bb.y); acc[a][1]=mk2(bb.z,bb.w); }
    for(int k=0;k<128;k+=4){
      float4 w0=*(const float4*)(pW1 + (size_t)(k+0)*128 + j0);
      float4 w1=*(const float4*)(pW1 + (size_t)(k+1)*128 + j0);
      float4 w2=*(const float4*)(pW1 + (size_t)(k+2)*128 + j0);
      float4 w3=*(const float4*)(pW1 + (size_t)(k+3)*128 + j0);
      v2f w0a=mk2(w0.x,w0.y), w0b=mk2(w0.z,w0.w);
      v2f w1a=mk2(w1.x,w1.y), w1b=mk2(w1.z,w1.w);
      v2f w2a=mk2(w2.x,w2.y), w2b=mk2(w2.z,w2.w);
      v2f w3a=mk2(w3.x,w3.y), w3b=mk2(w3.z,w3.w);
      #pragma unroll
      for(int a=0;a<4;a++){
        float4 m4=*(const float4*)(B0 + (eg*4+a)*ST + k);
        v2f hx=mk2(m4.x,m4.x), hy=mk2(m4.y,m4.y), hz=mk2(m4.z,m4.z), hw=mk2(m4.w,m4.w);
        acc[a][0]=fma2(hx,w0a,acc[a][0]); acc[a][1]=fma2(hx,w0b,acc[a][1]);
        acc[a][0]=fma2(hy,w1a,acc[a][0]); acc[a][1]=fma2(hy,w1b,acc[a][1]);
        acc[a][0]=fma2(hz,w2a,acc[a][0]); acc[a][1]=fma2(hz,w2b,acc[a][1]);
        acc[a][0]=fma2(hw,w3a,acc[a][0]); acc[a][1]=fma2(hw,w3b,acc[a][1]);
      }
    }
    #pragma unroll
    for(int a=0;a<4;a++){
      const int e = eg*4+a;
      *(float4*)(B2 + e*ST + j0) = make_float4(frelu(acc[a][0].x),frelu(acc[a][0].y),
                                               frelu(acc[a][1].x),frelu(acc[a][1].y));
    }
  }
  __syncthreads();   // B2(q) row e1 read cross-wave origin in Ph6

  // Ph6: pm = q@pW2 + pb2 -> REGISTERS (cols q1, q1+8 — consumed by same thread in Ph7)
  float pmA, pmB;
  {
    v2f acc = mk2(pb2[q1], pb2[q1+8]);
    const float* qp = B2 + e1*ST;
    for(int k=0;k<128;k+=4){
      float4 q4 = *(const float4*)(qp + k);
      v2f wa=mk2(pW2[(k+0)*16+q1], pW2[(k+0)*16+q1+8]);
      v2f wb=mk2(pW2[(k+1)*16+q1], pW2[(k+1)*16+q1+8]);
      v2f wc=mk2(pW2[(k+2)*16+q1], pW2[(k+2)*16+q1+8]);
      v2f wd=mk2(pW2[(k+3)*16+q1], pW2[(k+3)*16+q1+8]);
      acc=fma2(mk2(q4.x,q4.x),wa,acc);
      acc=fma2(mk2(q4.y,q4.y),wb,acc);
      acc=fma2(mk2(q4.z,q4.z),wc,acc);
      acc=fma2(mk2(q4.w,q4.w),wd,acc);
    }
    pmA = acc.x; pmB = acc.y;
  }
  // no barrier: Ph7 overwrites row e1 of B2, which only this wave read in Ph6
  // (same-wave DS ordering keeps the q-reads ahead of the pos_m-writes)

  // Ph7: pos_m = v_ij * pm (both from registers) -> B2 (SORTED=0: atomic scatter)
  {
    float4 o0 = make_float4(a0[0].x*pmA, a0[0].y*pmA, a0[1].x*pmA, a0[1].y*pmA);
    float4 o1 = make_float4(a0[2].x*pmA, a0[2].y*pmA, a0[3].x*pmA, a0[3].y*pmA);
    float4 o2 = make_float4(a1[0].x*pmB, a1[0].y*pmB, a1[1].x*pmB, a1[1].y*pmB);
    float4 o3 = make_float4(a1[2].x*pmB, a1[2].y*pmB, a1[3].x*pmB, a1[3].y*pmB);
    if(SORTED){
      *(float4*)(B2 + e1*ST + q1*8)       = o0;
      *(float4*)(B2 + e1*ST + q1*8+4)     = o1;
      *(float4*)(B2 + e1*ST + (q1+8)*8)   = o2;
      *(float4*)(B2 + e1*ST + (q1+8)*8+4) = o3;
    } else {
      float* pg = Pagg + (size_t)sR[e1]*128;
      atomicAdd(pg+q1*8+0,o0.x); atomicAdd(pg+q1*8+1,o0.y);
      atomicAdd(pg+q1*8+2,o0.z); atomicAdd(pg+q1*8+3,o0.w);
      atomicAdd(pg+q1*8+4,o1.x); atomicAdd(pg+q1*8+5,o1.y);
      atomicAdd(pg+q1*8+6,o1.z); atomicAdd(pg+q1*8+7,o1.w);
      atomicAdd(pg+(q1+8)*8+0,o2.x); atomicAdd(pg+(q1+8)*8+1,o2.y);
      atomicAdd(pg+(q1+8)*8+2,o2.z); atomicAdd(pg+(q1+8)*8+3,o2.w);
      atomicAdd(pg+(q1+8)*8+4,o3.x); atomicAdd(pg+(q1+8)*8+5,o3.y);
      atomicAdd(pg+(q1+8)*8+6,o3.z); atomicAdd(pg+(q1+8)*8+7,o3.w);
    }
  }

  // Ph8 (SORTED only): rec-segmented reduce -> one atomicAdd per (segment, column).
  if(SORTED){
    __syncthreads();
    const float* src = (t<128) ? B0 : B2;
    float* dst = (t<128) ? Magg : Pagg;
    const int j = t&127;
    float run = 0.f;
    int cr = sR[0];
    #pragma unroll 4
    for(int e=0;e<ET;e++){
      const int r = sR[e];
      if(r!=cr){
        atomicAdd(&dst[(size_t)cr*128 + j], run);
        run = 0.f; cr = r;
      }
      run += src[e*ST + j];
    }
    atomicAdd(&dst[(size_t)cr*128 + j], run);
  }
}

// ---------------- node kernel (R6/R8 version — coalesced row-major weights) ----------------
__global__ __launch_bounds__(256) void k_node(
    const float* __restrict__ s, const float* __restrict__ v,
    const float* __restrict__ uW1, const float* __restrict__ ub1,
    const float* __restrict__ uW2, const float* __restrict__ ub2,
    const float* __restrict__ glw, const float* __restrict__ glb,
    const float* __restrict__ grw, const float* __restrict__ grb,
    const float* __restrict__ gow, const float* __restrict__ gob,
    const float* __restrict__ lna,
    const float* __restrict__ mIn, const float* __restrict__ pIn,
    const int* __restrict__ degS,
    float* __restrict__ outS, float* __restrict__ outV)
{
  __shared__ float sX[16*256];
  __shared__ float sT[16*128];
  __shared__ float sP[16*128];
  __shared__ float sG[16*128];
  __shared__ float sNrm[256];
  __shared__ float sInv[16];
  const int t = threadIdx.x;
  const int nb = blockIdx.x*16;
  if(t<16) sInv[t] = rsqrtf((float)degS[nb+t]);
  __syncthreads();
  for(int i=t;i<16*256;i+=256){
    int n=i>>8, c=i&255;
    sX[i] = (c<128) ? s[(size_t)(nb+n)*128 + c]
                    : mIn[(size_t)(nb+n)*128 + (c-128)]*sInv[n];
  }
  for(int i=t;i<16*128;i+=256) sP[i] = pIn[(size_t)nb*128 + i]*sInv[i>>7];
  __syncthreads();
  // u1: relu(x@uW1+b1)  (packed over k pairs)
  {
    const int j = t&127, ng = t>>7;
    v2f acc[8]; const float bb=ub1[j];
    #pragma unroll
    for(int n=0;n<8;n++) acc[n]=mk2(bb,0.f);
    for(int k=0;k<256;k+=2){
      v2f w = mk2(uW1[(size_t)k*128+j], uW1[(size_t)(k+1)*128+j]);
      #pragma unroll
      for(int n=0;n<8;n++){
        v2f x = *(const v2f*)(sX + (ng*8+n)*256 + k);
        acc[n] = fma2(x, w, acc[n]);
      }
    }
    #pragma unroll
    for(int n=0;n<8;n++) sT[(ng*8+n)*128 + j] = frelu(acc[n].x + acc[n].y);
  }
  __syncthreads();
  // u2 + residual -> s_new  (packed over k pairs)
  {
    const int j = t&127, ng = t>>7;
    v2f acc[8]; const float bb=ub2[j];
    #pragma unroll
    for(int n=0;n<8;n++) acc[n]=mk2(bb,0.f);
    for(int k=0;k<128;k+=2){
      v2f w = mk2(uW2[(size_t)k*128+j], uW2[(size_t)(k+1)*128+j]);
      #pragma unroll
      for(int n=0;n<8;n++){
        v2f x = *(const v2f*)(sT + (ng*8+n)*128 + k);
        acc[n] = fma2(x, w, acc[n]);
      }
    }
    #pragma unroll
    for(int n=0;n<8;n++){
      const size_t r = (size_t)(nb + ng*8 + n)*128 + j;
      outS[r] = s[r] + acc[n].x + acc[n].y;
    }
  }
  float vo[8];
  {
    const int n = t>>4, o = t&15;
    float vl[8], vr[8];
    #pragma unroll
    for(int b=0;b<8;b++){vl[b]=0.f; vr[b]=0.f;}
    vl[0]=glb[o]; vr[0]=grb[o];
    #pragma unroll
    for(int c=0;c<16;c++){
      float4 pa=*(const float4*)(sP + n*128 + c*8);
      float4 pb=*(const float4*)(sP + n*128 + c*8 + 4);
      float4 ga=*(const float4*)(glw + (o*16+c)*4);
      float4 gb=*(const float4*)(grw + (o*16+c)*4);
      vl[0]+=pa.x*ga.x; vl[1]+=pa.y*ga.y; vl[2]+=pa.z*ga.y; vl[3]+=pa.w*ga.y;
      vl[4]+=pb.x*ga.z; vl[5]+=pb.y*ga.z; vl[6]+=pb.z*ga.z; vl[7]+=pb.w*ga.w;
      vr[0]+=pa.x*gb.x; vr[1]+=pa.y*gb.y; vr[2]+=pa.z*gb.y; vr[3]+=pa.w*gb.y;
      vr[4]+=pb.x*gb.z; vr[5]+=pb.y*gb.z; vr[6]+=pb.z*gb.z; vr[7]+=pb.w*gb.w;
    }
    float g[8];
    #pragma unroll
    for(int b=0;b<8;b++) g[b]=0.f;
    const int MASKS[8]={0,1,2,4,3,5,6,7};
    #pragma unroll
    for(int i=0;i<8;i++){
      #pragma unroll
      for(int jj=0;jj<8;jj++){
        const int a=MASKS[i], b=MASKS[jj];
        const int kk=MASKS[a^b];
        int sg=1;
        for(int tt=a>>1; tt; tt>>=1) if(__popc(tt&b)&1) sg=-sg;
        const float pr = vl[i]*vr[jj];
        g[kk] += (sg>0)? pr : -pr;
      }
    }
    *(float4*)(sG + n*128 + o*8)     = make_float4(g[0],g[1],g[2],g[3]);
    *(float4*)(sG + n*128 + o*8 + 4) = make_float4(g[4],g[5],g[6],g[7]);
  }
  __syncthreads();
  {
    const int n = t>>4, o = t&15;
    #pragma unroll
    for(int b=0;b<8;b++) vo[b]=0.f;
    vo[0]=gob[o];
    #pragma unroll
    for(int c=0;c<32;c++){
      const float* src = (c<16) ? (sG + n*128 + c*8) : (sP + n*128 + (c-16)*8);
      float4 sa=*(const float4*)(src);
      float4 sb=*(const float4*)(src+4);
      float4 gw=*(const float4*)(gow + (o*32+c)*4);
      vo[0]+=sa.x*gw.x; vo[1]+=sa.y*gw.y; vo[2]+=sa.z*gw.y; vo[3]+=sa.w*gw.y;
      vo[4]+=sb.x*gw.z; vo[5]+=sb.y*gw.z; vo[6]+=sb.z*gw.z; vo[7]+=sb.w*gw.w;
    }
    float ssum=0.f;
    #pragma unroll
    for(int b=0;b<8;b++) ssum+=vo[b]*vo[b];
    sNrm[t]=sqrtf(ssum);
  }
  __syncthreads();
  {
    const int n = t>>4, o = t&15;
    float mn=0.f;
    #pragma unroll
    for(int c=0;c<16;c++) mn += sNrm[n*16+c];
    mn = mn*(1.f/16.f) + 1e-6f;
    const float sc = lna[o]/mn;
    const size_t base = (size_t)(nb+n)*128 + o*8;
    float4 v0=*(const float4*)(v+base);
    float4 v1=*(const float4*)(v+base+4);
    *(float4*)(outV+base)   = make_float4(vo[0]*sc+v0.x, vo[1]*sc+v0.y, vo[2]*sc+v0.z, vo[3]*sc+v0.w);
    *(float4*)(outV+base+4) = make_float4(vo[4]*sc+v1.x, vo[5]*sc+v1.y, vo[6]*sc+v1.z, vo[7]*sc+v1.w);
  }
}

extern "C" void kernel_launch(void* const* d_in, const int* in_sizes, int n_in,
                              void* d_out, int out_size, void* d_ws, size_t ws_size,
                              hipStream_t stream){
  (void)in_sizes; (void)n_in; (void)out_size;
  const float* s    = (const float*)d_in[0];
  const float* v    = (const float*)d_in[1];
  const int*   eidx = (const int*)d_in[2];
  const float* Wvw  = (const float*)d_in[3];
  const float* Wvb  = (const float*)d_in[4];
  const float* mnW1 = (const float*)d_in[5];
  const float* mnb1 = (const float*)d_in[6];
  const float* mnW2 = (const float*)d_in[7];
  const float* mnb2 = (const float*)d_in[8];
  const float* pnW1 = (const float*)d_in[9];
  const float* pnb1 = (const float*)d_in[10];
  const float* pnW2 = (const float*)d_in[11];
  const float* pnb2 = (const float*)d_in[12];
  const float* unW1 = (const float*)d_in[13];
  const float* unb1 = (const float*)d_in[14];
  const float* unW2 = (const float*)d_in[15];
  const float* unb2 = (const float*)d_in[16];
  const float* glw  = (const float*)d_in[17];
  const float* glb  = (const float*)d_in[18];
  const float* grw  = (const float*)d_in[19];
  const float* grb  = (const float*)d_in[20];
  const float* gow  = (const float*)d_in[21];
  const float* gob  = (const float*)d_in[22];
  const float* lna  = (const float*)d_in[23];

  float* outS = (float*)d_out;
  float* outV = outS + (size_t)NN*128;
  float* A    = outS;            // A/Bn stage in d_out (dead until k_node writes)
  float* Bn   = outV;

  const size_t need = ((size_t)2*NN*128)*sizeof(float) + ((size_t)3*NN + NE)*sizeof(int);

  float* Magg = (float*)d_ws;
  float* Pagg = Magg + (size_t)NN*128;
  int* degS = (int*)(Pagg + (size_t)NN*128);
  int* cntR = degS + NN;
  int* cur  = cntR + NN;
  int* eord = cur + NN;

  if(ws_size >= need){
    (void)hipMemsetAsync(Magg, 0, (size_t)2*NN*128*sizeof(float) + (size_t)2*NN*sizeof(int), stream);
    k_hist<<<(NE+255)/256, 256, 0, stream>>>(eidx, degS, cntR, 1);
    k_scan<<<1, 256, 0, stream>>>(cntR, cur);
    k_fill<<<(NE+255)/256, 256, 0, stream>>>(eidx, cur, eord);
    k_ab<<<NN/8, 256, 0, stream>>>(s, mnW1, A, Bn);
    k_edge<1><<<NE/ET, 256, 0, stream>>>(v, eidx, Wvw, Wvb, mnW1 + 256*128, mnb1,
                                         mnW2, mnb2, pnW1, pnb1, pnW2, pnb2,
                                         A, Bn, eord, Magg, Pagg);
    k_node<<<NN/16, 256, 0, stream>>>(s, v, unW1, unb1, unW2, unb2,
                                      glw, glb, grw, grb, gow, gob, lna,
                                      Magg, Pagg, degS, outS, outV);
  } else {
    (void)hipMemsetAsync(Magg, 0, (size_t)2*NN*128*sizeof(float) + (size_t)NN*sizeof(int), stream);
    k_hist<<<(NE+255)/256, 256, 0, stream>>>(eidx, degS, (int*)0, 0);
    k_ab<<<NN/8, 256, 0, stream>>>(s, mnW1, A, Bn);
    k_edge<0><<<NE/ET, 256, 0, stream>>>(v, eidx, Wvw, Wvb, mnW1 + 256*128, mnb1,
                                         mnW2, mnb2, pnW1, pnb1, pnW2, pnb2,
                                         A, Bn, (int*)0, Magg, Pagg);
    k_node<<<NN/16, 256, 0, stream>>>(s, v, unW1, unb1, unW2, unb2,
                                      glw, glb, grw, grb, gow, gob, lna,
                                      Magg, Pagg, degS, outS, outV);
  }
}

// Round 11
// 725.821 us; speedup vs baseline: 1.2172x; 1.2172x over previous
//
#include <hip/hip_runtime.h>
#include <hip/hip_fp16.h>
#include <math.h>

#define NN 20000
#define NE 320000
#define ET 32          // edges per tile
#define ST 132         // LDS row stride in floats
#define SH 136         // LDS row stride in halfs (fp16 buffers)

typedef float v2f __attribute__((ext_vector_type(2)));
typedef float f32x4 __attribute__((ext_vector_type(4)));
typedef _Float16 f16x8 __attribute__((ext_vector_type(8)));
__device__ __forceinline__ v2f fma2(v2f a, v2f b, v2f c){ return __builtin_elementwise_fma(a,b,c); }
__device__ __forceinline__ v2f mk2(float x, float y){ v2f r; r.x=x; r.y=y; return r; }
__device__ __forceinline__ float frelu(float x){ return fmaxf(x, 0.f); }

// ---------------- histograms ----------------
__global__ void k_hist(const int* __restrict__ eidx, int* __restrict__ degS,
                       int* __restrict__ cntR, int mode){
  int t = blockIdx.x*256 + threadIdx.x;
  if(t < NE){
    atomicAdd(&degS[eidx[t]], 1);
    if(mode) atomicAdd(&cntR[eidx[NE+t]], 1);
  }
}

// ---------------- exclusive scan of cntR -> cur[N] (single block) ----------------
__global__ __launch_bounds__(256) void k_scan(const int* __restrict__ cntR,
                                              int* __restrict__ cur){
  __shared__ int part[256];
  __shared__ int pre[256];
  const int t = threadIdx.x;
  const int start = t*80, end = min(start+80, NN);
  int sm = 0;
  for(int n=start;n<end;n++) sm += cntR[n];
  part[t] = sm;
  __syncthreads();
  if(t==0){ int r=0; for(int i=0;i<256;i++){ pre[i]=r; r+=part[i]; } }
  __syncthreads();
  int run = pre[t];
  for(int n=start;n<end;n++){ cur[n]=run; run += cntR[n]; }
}

// ---------------- scatter edge ids into rec-sorted order ----------------
__global__ void k_fill(const int* __restrict__ eidx, int* __restrict__ cur,
                       int* __restrict__ eord){
  int e = blockIdx.x*256 + threadIdx.x;
  if(e < NE){
    int r = eidx[NE+e];
    int p = atomicAdd(&cur[r], 1);
    eord[p] = e;
  }
}

// ---------------- pack W2, pW1 into fp16 B-fragment order for mfma_16x16x32 ----------------
// Bpack[((ntile*4 + ktile)*64 + lane)*8 + j] = W[k][n], n = ntile*16 + (lane&15),
// k = ktile*32 + (lane>>4)*8 + j.  One dwordx4 per lane per MFMA, fully coalesced.
__global__ __launch_bounds__(256) void k_prep(const float* __restrict__ W2,
                                              const float* __restrict__ pW1,
                                              _Float16* __restrict__ W2h,
                                              _Float16* __restrict__ pW1h){
  int i = blockIdx.x*256 + threadIdx.x;
  if(i < 16384){
    int nt = i>>11, rem = i&2047, kt = rem>>9, r2 = rem&511, lane = r2>>3, j = r2&7;
    int n = nt*16 + (lane&15);
    int k = kt*32 + (lane>>4)*8 + j;
    W2h[i]  = (_Float16)W2[k*128 + n];
    pW1h[i] = (_Float16)pW1[k*128 + n];
  }
}

// ---------------- per-node precompute: A = s@W1[0:128], B = s@W1[128:256] ----------------
__global__ __launch_bounds__(256) void k_ab(const float* __restrict__ s,
                                            const float* __restrict__ W1,
                                            float* __restrict__ A,
                                            float* __restrict__ B){
  __shared__ float sx[8*128];
  const int nb = blockIdx.x*8;
  for(int i=threadIdx.x; i<8*128; i+=256) sx[i] = s[(size_t)nb*128 + i];
  __syncthreads();
  const int col = threadIdx.x;
  const int j = col & 127;
  const float* w = W1 + (col < 128 ? 0 : 128*128) + j;
  v2f acc[4];
  #pragma unroll
  for(int n=0;n<4;n++) acc[n]=mk2(0.f,0.f);
  for(int k=0;k<128;k++){
    float wv = w[(size_t)k*128];
    v2f wv2 = mk2(wv, wv);
    #pragma unroll
    for(int n=0;n<4;n++){
      v2f x = mk2(sx[(2*n)*128+k], sx[(2*n+1)*128+k]);
      acc[n] = fma2(x, wv2, acc[n]);
    }
  }
  float* dst = (col<128 ? A : B) + (size_t)nb*128 + j;
  #pragma unroll
  for(int n=0;n<4;n++){
    dst[(size_t)(2*n)*128]   = acc[n].x;
    dst[(size_t)(2*n+1)*128] = acc[n].y;
  }
}

// ======================= MFMA edge kernel (rec-sorted path) =======================
// R8 barrier discipline. Ph4/Ph5 (the two 32x128x128 GEMMs, 80% of edge FLOPs) run on
// matrix cores in fp16 (fp32 accumulate). h/m live in fp16 LDS buffer Hh (A-fragments:
// one ds_read_b128 per lane, 2-way bank conflict = free). Weights pre-packed (k_prep).
__global__ __launch_bounds__(256) void k_edgeM(
    const float* __restrict__ v, const int* __restrict__ eidx,
    const float* __restrict__ Wvw, const float* __restrict__ Wvb,
    const float* __restrict__ W1c, const float* __restrict__ b1,
    const float* __restrict__ b2,  const float* __restrict__ pb1,
    const float* __restrict__ pW2, const float* __restrict__ pb2,
    const float* __restrict__ A,   const float* __restrict__ Bn,
    const int* __restrict__ eord,
    const _Float16* __restrict__ W2h, const _Float16* __restrict__ pW1h,
    float* __restrict__ Magg, float* __restrict__ Pagg)
{
  __shared__ float B0[ET*ST];        // d -> m (fp32, Ph8 source)
  __shared__ float B2[ET*ST];        // q -> pos_m
  __shared__ _Float16 Hh[ET*SH];     // h (Ph4 A-operand) -> m (Ph5 A-operand)
  __shared__ float sEP[ET*16];       // edge_attr, then pm
  __shared__ int sS[ET], sR[ET];
  const int t  = threadIdx.x;
  const int e0 = blockIdx.x * ET;

  if(t<ET){
    int e = eord[e0+t];
    sS[t]=eidx[e]; sR[t]=eidx[NE+e];
  }
  __syncthreads();

  const int e1 = t>>3, q1 = t&7;     // Ph1/Ph2/Ph6/Ph7 mapping
  const int wv = t>>6, lane = t&63;  // MFMA mapping
  const int mcol = lane&15, quad = lane>>4;

  // Ph1: d = v[rec] - v[send] -> B0
  {
    const float4* vs = (const float4*)(v + (size_t)sS[e1]*128);
    const float4* vr = (const float4*)(v + (size_t)sR[e1]*128);
    #pragma unroll
    for(int i=0;i<4;i++){
      int f = q1 + i*8;
      float4 a = vr[f], b = vs[f];
      *(float4*)(B0 + e1*ST + f*4) = make_float4(a.x-b.x, a.y-b.y, a.z-b.z, a.w-b.w);
    }
  }
  __syncthreads();

  // Ph2: v_ij = mv_linear(d, Wv) -> REGISTERS; edge_attr -> sEP
  v2f a0[4], a1[4];                  // blade pairs, live through Ph7
  {
    #pragma unroll
    for(int b=0;b<4;b++){ a0[b]=mk2(0.f,0.f); a1[b]=mk2(0.f,0.f); }
    a0[0].x=Wvb[q1]; a1[0].x=Wvb[q1+8];
    const float* dp = B0 + e1*ST;
    #pragma unroll
    for(int c=0;c<16;c++){
      float4 da=*(const float4*)(dp + c*8);
      float4 db=*(const float4*)(dp + c*8 + 4);
      float4 g0=*(const float4*)(Wvw + (q1*16+c)*4);
      float4 g1=*(const float4*)(Wvw + ((q1+8)*16+c)*4);
      a0[0]=fma2(mk2(da.x,da.y), mk2(g0.x,g0.y), a0[0]);
      a0[1]=fma2(mk2(da.z,da.w), mk2(g0.y,g0.y), a0[1]);
      a0[2]=fma2(mk2(db.x,db.y), mk2(g0.z,g0.z), a0[2]);
      a0[3]=fma2(mk2(db.z,db.w), mk2(g0.z,g0.w), a0[3]);
      a1[0]=fma2(mk2(da.x,da.y), mk2(g1.x,g1.y), a1[0]);
      a1[1]=fma2(mk2(da.z,da.w), mk2(g1.y,g1.y), a1[1]);
      a1[2]=fma2(mk2(db.x,db.y), mk2(g1.z,g1.z), a1[2]);
      a1[3]=fma2(mk2(db.z,db.w), mk2(g1.z,g1.w), a1[3]);
    }
    v2f s0=mk2(0.f,0.f), s1=mk2(0.f,0.f);
    #pragma unroll
    for(int b=0;b<4;b++){ s0=fma2(a0[b],a0[b],s0); s1=fma2(a1[b],a1[b],s1); }
    sEP[e1*16+q1]=s0.x+s0.y; sEP[e1*16+q1+8]=s1.x+s1.y;
  }
  __syncthreads();

  // Ph3: h = relu(A[send] + Bn[rec] + ea@W1c + b1) -> Hh (fp16)
  {
    const int j = t&127, eg = t>>7;
    v2f w1c[8];
    #pragma unroll
    for(int c=0;c<8;c++) w1c[c]=mk2(W1c[(size_t)(2*c)*128 + j], W1c[(size_t)(2*c+1)*128 + j]);
    const float bb = b1[j];
    for(int ei=0; ei<16; ei++){
      const int e = eg*16 + ei;
      const float base = A[(size_t)sS[e]*128 + j] + Bn[(size_t)sR[e]*128 + j] + bb;
      v2f accv = mk2(0.f,0.f);
      const v2f* eap = (const v2f*)(sEP + e*16);
      #pragma unroll
      for(int c=0;c<8;c++) accv = fma2(eap[c], w1c[c], accv);
      Hh[e*SH + j] = (_Float16)frelu(base + accv.x + accv.y);
    }
  }
  __syncthreads();

  // Ph4a: m = h@W2 (MFMA). Wave handles 4 of the 16 (M16,N16) tiles; K=128 in 4 steps.
  f32x4 accm[4];
  {
    #pragma unroll
    for(int tile=0;tile<4;tile++){
      const int tid = wv*4+tile, mt = tid&1, nt = tid>>1;
      f32x4 acc = {0.f,0.f,0.f,0.f};
      #pragma unroll
      for(int kt=0;kt<4;kt++){
        f16x8 af = *(const f16x8*)&Hh[(mt*16+mcol)*SH + kt*32 + quad*8];
        f16x8 bf = *(const f16x8*)&W2h[((nt*4+kt)*64+lane)*8];
        acc = __builtin_amdgcn_mfma_f32_16x16x32_f16(af, bf, acc, 0,0,0);
      }
      accm[tile]=acc;
    }
  }
  __syncthreads();   // all Hh(h) reads complete before overwrite

  // Ph4b: m += b2 -> B0 (fp32, Ph8 source) and Hh (fp16, Ph5 A-operand)
  {
    #pragma unroll
    for(int tile=0;tile<4;tile++){
      const int tid = wv*4+tile, mt = tid&1, nt = tid>>1;
      const int n = nt*16+mcol;
      const float bbv = b2[n];
      #pragma unroll
      for(int r=0;r<4;r++){
        const int e = mt*16 + quad*4 + r;
        const float val = accm[tile][r] + bbv;
        B0[e*ST + n] = val;
        Hh[e*SH + n] = (_Float16)val;
      }
    }
  }
  __syncthreads();

  // Ph5: q = relu(m@pW1 + pb1) -> B2 (MFMA)
  {
    #pragma unroll
    for(int tile=0;tile<4;tile++){
      const int tid = wv*4+tile, mt = tid&1, nt = tid>>1;
      f32x4 acc = {0.f,0.f,0.f,0.f};
      #pragma unroll
      for(int kt=0;kt<4;kt++){
        f16x8 af = *(const f16x8*)&Hh[(mt*16+mcol)*SH + kt*32 + quad*8];
        f16x8 bf = *(const f16x8*)&pW1h[((nt*4+kt)*64+lane)*8];
        acc = __builtin_amdgcn_mfma_f32_16x16x32_f16(af, bf, acc, 0,0,0);
      }
      const int n = nt*16+mcol;
      const float bbv = pb1[n];
      #pragma unroll
      for(int r=0;r<4;r++){
        const int e = mt*16+quad*4+r;
        B2[e*ST + n] = frelu(acc[r] + bbv);
      }
    }
  }
  __syncthreads();

  // Ph6: pm = q@pW2 + pb2 -> sEP (packed: cols q1 and q1+8 as lanes)
  {
    v2f acc = mk2(pb2[q1], pb2[q1+8]);
    const float* qp = B2 + e1*ST;
    for(int k=0;k<128;k+=4){
      float4 q4 = *(const float4*)(qp + k);
      v2f wa=mk2(pW2[(k+0)*16+q1], pW2[(k+0)*16+q1+8]);
      v2f wb=mk2(pW2[(k+1)*16+q1], pW2[(k+1)*16+q1+8]);
      v2f wc=mk2(pW2[(k+2)*16+q1], pW2[(k+2)*16+q1+8]);
      v2f wd=mk2(pW2[(k+3)*16+q1], pW2[(k+3)*16+q1+8]);
      acc=fma2(mk2(q4.x,q4.x),wa,acc);
      acc=fma2(mk2(q4.y,q4.y),wb,acc);
      acc=fma2(mk2(q4.z,q4.z),wc,acc);
      acc=fma2(mk2(q4.w,q4.w),wd,acc);
    }
    sEP[e1*16+q1]=acc.x; sEP[e1*16+q1+8]=acc.y;
  }
  __syncthreads();

  // Ph7: pos_m = v_ij * pm (v_ij from registers) -> B2
  {
    const float pmA = sEP[e1*16+q1], pmB = sEP[e1*16+q1+8];
    *(float4*)(B2 + e1*ST + q1*8)       = make_float4(a0[0].x*pmA, a0[0].y*pmA, a0[1].x*pmA, a0[1].y*pmA);
    *(float4*)(B2 + e1*ST + q1*8+4)     = make_float4(a0[2].x*pmA, a0[2].y*pmA, a0[3].x*pmA, a0[3].y*pmA);
    *(float4*)(B2 + e1*ST + (q1+8)*8)   = make_float4(a1[0].x*pmB, a1[0].y*pmB, a1[1].x*pmB, a1[1].y*pmB);
    *(float4*)(B2 + e1*ST + (q1+8)*8+4) = make_float4(a1[2].x*pmB, a1[2].y*pmB, a1[3].x*pmB, a1[3].y*pmB);
  }
  __syncthreads();

  // Ph8: rec-segmented reduce -> one atomicAdd per (segment, column)
  {
    const float* src = (t<128) ? B0 : B2;
    float* dst = (t<128) ? Magg : Pagg;
    const int j = t&127;
    float run = 0.f;
    int cr = sR[0];
    #pragma unroll 4
    for(int e=0;e<ET;e++){
      const int r = sR[e];
      if(r!=cr){
        atomicAdd(&dst[(size_t)cr*128 + j], run);
        run = 0.f; cr = r;
      }
      run += src[e*ST + j];
    }
    atomicAdd(&dst[(size_t)cr*128 + j], run);
  }
}

// ---------------- fallback full-VALU atomic edge kernel (proven R0/R8 path) ----------------
__global__ __launch_bounds__(256) void k_edge0(
    const float* __restrict__ v, const int* __restrict__ eidx,
    const float* __restrict__ Wvw, const float* __restrict__ Wvb,
    const float* __restrict__ W1c, const float* __restrict__ b1,
    const float* __restrict__ W2,  const float* __restrict__ b2,
    const float* __restrict__ pW1, const float* __restrict__ pb1,
    const float* __restrict__ pW2, const float* __restrict__ pb2,
    const float* __restrict__ A,   const float* __restrict__ Bn,
    float* __restrict__ Magg, float* __restrict__ Pagg)
{
  __shared__ float B0[ET*ST];
  __shared__ float B2[ET*ST];
  __shared__ float sEP[ET*16];
  __shared__ int sS[ET], sR[ET];
  const int t  = threadIdx.x;
  const int e0 = blockIdx.x * ET;
  if(t<ET){ sS[t]=eidx[e0+t]; sR[t]=eidx[NE+e0+t]; }
  __syncthreads();
  const int e1 = t>>3, q1 = t&7;
  {
    const float4* vs = (const float4*)(v + (size_t)sS[e1]*128);
    const float4* vr = (const float4*)(v + (size_t)sR[e1]*128);
    #pragma unroll
    for(int i=0;i<4;i++){
      int f = q1 + i*8;
      float4 a = vr[f], b = vs[f];
      *(float4*)(B0 + e1*ST + f*4) = make_float4(a.x-b.x, a.y-b.y, a.z-b.z, a.w-b.w);
    }
  }
  __syncthreads();
  v2f a0[4], a1[4];
  {
    #pragma unroll
    for(int b=0;b<4;b++){ a0[b]=mk2(0.f,0.f); a1[b]=mk2(0.f,0.f); }
    a0[0].x=Wvb[q1]; a1[0].x=Wvb[q1+8];
    const float* dp = B0 + e1*ST;
    #pragma unroll
    for(int c=0;c<16;c++){
      float4 da=*(const float4*)(dp + c*8);
      float4 db=*(const float4*)(dp + c*8 + 4);
      float4 g0=*(const float4*)(Wvw + (q1*16+c)*4);
      float4 g1=*(const float4*)(Wvw + ((q1+8)*16+c)*4);
      a0[0]=fma2(mk2(da.x,da.y), mk2(g0.x,g0.y), a0[0]);
      a0[1]=fma2(mk2(da.z,da.w), mk2(g0.y,g0.y), a0[1]);
      a0[2]=fma2(mk2(db.x,db.y), mk2(g0.z,g0.z), a0[2]);
      a0[3]=fma2(mk2(db.z,db.w), mk2(g0.z,g0.w), a0[3]);
      a1[0]=fma2(mk2(da.x,da.y), mk2(g1.x,g1.y), a1[0]);
      a1[1]=fma2(mk2(da.z,da.w), mk2(g1.y,g1.y), a1[1]);
      a1[2]=fma2(mk2(db.x,db.y), mk2(g1.z,g1.z), a1[2]);
      a1[3]=fma2(mk2(db.z,db.w), mk2(g1.z,g1.w), a1[3]);
    }
    v2f s0=mk2(0.f,0.f), s1=mk2(0.f,0.f);
    #pragma unroll
    for(int b=0;b<4;b++){ s0=fma2(a0[b],a0[b],s0); s1=fma2(a1[b],a1[b],s1); }
    sEP[e1*16+q1]=s0.x+s0.y; sEP[e1*16+q1+8]=s1.x+s1.y;
  }
  __syncthreads();
  {
    const int j = t&127, eg = t>>7;
    v2f w1c[8];
    #pragma unroll
    for(int c=0;c<8;c++) w1c[c]=mk2(W1c[(size_t)(2*c)*128 + j], W1c[(size_t)(2*c+1)*128 + j]);
    const float bb = b1[j];
    for(int ei=0; ei<16; ei++){
      const int e = eg*16 + ei;
      const float base = A[(size_t)sS[e]*128 + j] + Bn[(size_t)sR[e]*128 + j] + bb;
      v2f accv = mk2(0.f,0.f);
      const v2f* eap = (const v2f*)(sEP + e*16);
      #pragma unroll
      for(int c=0;c<8;c++) accv = fma2(eap[c], w1c[c], accv);
      B2[e*ST + j] = frelu(base + accv.x + accv.y);
    }
  }
  __syncthreads();
  {
    const int jq = t&31, eg = t>>5;
    const int j0 = jq*4;
    float4 bb = *(const float4*)(b2 + j0);
    v2f acc[4][2];
    #pragma unroll
    for(int a=0;a<4;a++){ acc[a][0]=mk2(bb.x,bb.y); acc[a][1]=mk2(bb.z,bb.w); }
    for(int k=0;k<128;k+=4){
      float4 w0=*(const float4*)(W2 + (size_t)(k+0)*128 + j0);
      float4 w1=*(const float4*)(W2 + (size_t)(k+1)*128 + j0);
      float4 w2=*(const float4*)(W2 + (size_t)(k+2)*128 + j0);
      float4 w3=*(const float4*)(W2 + (size_t)(k+3)*128 + j0);
      v2f w0a=mk2(w0.x,w0.y), w0b=mk2(w0.z,w0.w);
      v2f w1a=mk2(w1.x,w1.y), w1b=mk2(w1.z,w1.w);
      v2f w2a=mk2(w2.x,w2.y), w2b=mk2(w2.z,w2.w);
      v2f w3a=mk2(w3.x,w3.y), w3b=mk2(w3.z,w3.w);
      #pragma unroll
      for(int a=0;a<4;a++){
        float4 h4=*(const float4*)(B2 + (eg*4+a)*ST + k);
        v2f hx=mk2(h4.x,h4.x), hy=mk2(h4.y,h4.y), hz=mk2(h4.z,h4.z), hw=mk2(h4.w,h4.w);
        acc[a][0]=fma2(hx,w0a,acc[a][0]); acc[a][1]=fma2(hx,w0b,acc[a][1]);
        acc[a][0]=fma2(hy,w1a,acc[a][0]); acc[a][1]=fma2(hy,w1b,acc[a][1]);
        acc[a][0]=fma2(hz,w2a,acc[a][0]); acc[a][1]=fma2(hz,w2b,acc[a][1]);
        acc[a][0]=fma2(hw,w3a,acc[a][0]); acc[a][1]=fma2(hw,w3b,acc[a][1]);
      }
    }
    #pragma unroll
    for(int a=0;a<4;a++){
      const int e = eg*4+a;
      *(float4*)(B0 + e*ST + j0) = make_float4(acc[a][0].x,acc[a][0].y,acc[a][1].x,acc[a][1].y);
      float* mg = Magg + (size_t)sR[e]*128 + j0;
      atomicAdd(mg+0, acc[a][0].x); atomicAdd(mg+1, acc[a][0].y);
      atomicAdd(mg+2, acc[a][1].x); atomicAdd(mg+3, acc[a][1].y);
    }
  }
  __syncthreads();
  {
    const int jq = t&31, eg = t>>5;
    const int j0 = jq*4;
    float4 bb = *(const float4*)(pb1 + j0);
    v2f acc[4][2];
    #pragma unroll
    for(int a=0;a<4;a++){ acc[a][0]=mk2(bb.x,bb.y); acc[a][1]=mk2(bb.z,bb.w); }
    for(int k=0;k<128;k+=4){
      float4 w0=*(const float4*)(pW1 + (size_t)(k+0)*128 + j0);
      float4 w1=*(const float4*)(pW1 + (size_t)(k+1)*128 + j0);
      float4 w2=*(const float4*)(pW1 + (size_t)(k+2)*128 + j0);
      float4 w3=*(const float4*)(pW1 + (size_t)(k+3)*128 + j0);
      v2f w0a=mk2(w0.x,w0.y), w0b=mk2(w0.z,w0.w);
      v2f w1a=mk2(w1.x,w1.y), w1b=mk2(w1.z,w1.w);
      v2f w2a=mk2(w2.x,w2.y), w2b=mk2(w2.z,w2.w);
      v2f w3a=mk2(w3.x,w3.y), w3b=mk2(w3.z,w3.w);
      #pragma unroll
      for(int a=0;a<4;a++){
        float4 m4=*(const float4*)(B0 + (eg*4+a)*ST + k);
        v2f hx=mk2(m4.x,m4.x), hy=mk2(m4.y,m4.y), hz=mk2(m4.z,m4.z), hw=mk2(m4.w,m4.w);
        acc[a][0]=fma2(hx,w0a,acc[a][0]); acc[a][1]=fma2(hx,w0b,acc[a][1]);
        acc[a][0]=fma2(hy,w1a,acc[a][0]); acc[a][1]=fma2(hy,w1b,acc[a][1]);
        acc[a][0]=fma2(hz,w2a,acc[a][0]); acc[a][1]=fma2(hz,w2b,acc[a][1]);
        acc[a][0]=fma2(hw,w3a,acc[a][0]); acc[a][1]=fma2(hw,w3b,acc[a][1]);
      }
    }
    #pragma unroll
    for(int a=0;a<4;a++){
      const int e = eg*4+a;
      *(float4*)(B2 + e*ST + j0) = make_float4(frelu(acc[a][0].x),frelu(acc[a][0].y),
                                               frelu(acc[a][1].x),frelu(acc[a][1].y));
    }
  }
  __syncthreads();
  {
    v2f acc = mk2(pb2[q1], pb2[q1+8]);
    const float* qp = B2 + e1*ST;
    for(int k=0;k<128;k+=4){
      float4 q4 = *(const float4*)(qp + k);
      v2f wa=mk2(pW2[(k+0)*16+q1], pW2[(k+0)*16+q1+8]);
      v2f wb=mk2(pW2[(k+1)*16+q1], pW2[(k+1)*16+q1+8]);
      v2f wc=mk2(pW2[(k+2)*16+q1], pW2[(k+2)*16+q1+8]);
      v2f wd=mk2(pW2[(k+3)*16+q1], pW2[(k+3)*16+q1+8]);
      acc=fma2(mk2(q4.x,q4.x),wa,acc);
      acc=fma2(mk2(q4.y,q4.y),wb,acc);
      acc=fma2(mk2(q4.z,q4.z),wc,acc);
      acc=fma2(mk2(q4.w,q4.w),wd,acc);
    }
    sEP[e1*16+q1]=acc.x; sEP[e1*16+q1+8]=acc.y;
  }
  __syncthreads();
  {
    const float pmA = sEP[e1*16+q1], pmB = sEP[e1*16+q1+8];
    float* pg = Pagg + (size_t)sR[e1]*128;
    float ov[16] = {a0[0].x*pmA,a0[0].y*pmA,a0[1].x*pmA,a0[1].y*pmA,
                    a0[2].x*pmA,a0[2].y*pmA,a0[3].x*pmA,a0[3].y*pmA,
                    a1[0].x*pmB,a1[0].y*pmB,a1[1].x*pmB,a1[1].y*pmB,
                    a1[2].x*pmB,a1[2].y*pmB,a1[3].x*pmB,a1[3].y*pmB};
    #pragma unroll
    for(int i=0;i<8;i++)  atomicAdd(pg+q1*8+i, ov[i]);
    #pragma unroll
    for(int i=0;i<8;i++)  atomicAdd(pg+(q1+8)*8+i, ov[8+i]);
  }
}

// ---------------- node kernel (R8 version) ----------------
__global__ __launch_bounds__(256) void k_node(
    const float* __restrict__ s, const float* __restrict__ v,
    const float* __restrict__ uW1, const float* __restrict__ ub1,
    const float* __restrict__ uW2, const float* __restrict__ ub2,
    const float* __restrict__ glw, const float* __restrict__ glb,
    const float* __restrict__ grw, const float* __restrict__ grb,
    const float* __restrict__ gow, const float* __restrict__ gob,
    const float* __restrict__ lna,
    const float* __restrict__ mIn, const float* __restrict__ pIn,
    const int* __restrict__ degS,
    float* __restrict__ outS, float* __restrict__ outV)
{
  __shared__ float sX[16*256];
  __shared__ float sT[16*128];
  __shared__ float sP[16*128];
  __shared__ float sG[16*128];
  __shared__ float sNrm[256];
  __shared__ float sInv[16];
  const int t = threadIdx.x;
  const int nb = blockIdx.x*16;
  if(t<16) sInv[t] = rsqrtf((float)degS[nb+t]);
  __syncthreads();
  for(int i=t;i<16*256;i+=256){
    int n=i>>8, c=i&255;
    sX[i] = (c<128) ? s[(size_t)(nb+n)*128 + c]
                    : mIn[(size_t)(nb+n)*128 + (c-128)]*sInv[n];
  }
  for(int i=t;i<16*128;i+=256) sP[i] = pIn[(size_t)nb*128 + i]*sInv[i>>7];
  __syncthreads();
  {
    const int j = t&127, ng = t>>7;
    v2f acc[8]; const float bb=ub1[j];
    #pragma unroll
    for(int n=0;n<8;n++) acc[n]=mk2(bb,0.f);
    for(int k=0;k<256;k+=2){
      v2f w = mk2(uW1[(size_t)k*128+j], uW1[(size_t)(k+1)*128+j]);
      #pragma unroll
      for(int n=0;n<8;n++){
        v2f x = *(const v2f*)(sX + (ng*8+n)*256 + k);
        acc[n] = fma2(x, w, acc[n]);
      }
    }
    #pragma unroll
    for(int n=0;n<8;n++) sT[(ng*8+n)*128 + j] = frelu(acc[n].x + acc[n].y);
  }
  __syncthreads();
  {
    const int j = t&127, ng = t>>7;
    v2f acc[8]; const float bb=ub2[j];
    #pragma unroll
    for(int n=0;n<8;n++) acc[n]=mk2(bb,0.f);
    for(int k=0;k<128;k+=2){
      v2f w = mk2(uW2[(size_t)k*128+j], uW2[(size_t)(k+1)*128+j]);
      #pragma unroll
      for(int n=0;n<8;n++){
        v2f x = *(const v2f*)(sT + (ng*8+n)*128 + k);
        acc[n] = fma2(x, w, acc[n]);
      }
    }
    #pragma unroll
    for(int n=0;n<8;n++){
      const size_t r = (size_t)(nb + ng*8 + n)*128 + j;
      outS[r] = s[r] + acc[n].x + acc[n].y;
    }
  }
  float vo[8];
  {
    const int n = t>>4, o = t&15;
    float vl[8], vr[8];
    #pragma unroll
    for(int b=0;b<8;b++){vl[b]=0.f; vr[b]=0.f;}
    vl[0]=glb[o]; vr[0]=grb[o];
    #pragma unroll
    for(int c=0;c<16;c++){
      float4 pa=*(const float4*)(sP + n*128 + c*8);
      float4 pb=*(const float4*)(sP + n*128 + c*8 + 4);
      float4 ga=*(const float4*)(glw + (o*16+c)*4);
      float4 gb=*(const float4*)(grw + (o*16+c)*4);
      vl[0]+=pa.x*ga.x; vl[1]+=pa.y*ga.y; vl[2]+=pa.z*ga.y; vl[3]+=pa.w*ga.y;
      vl[4]+=pb.x*ga.z; vl[5]+=pb.y*ga.z; vl[6]+=pb.z*ga.z; vl[7]+=pb.w*ga.w;
      vr[0]+=pa.x*gb.x; vr[1]+=pa.y*gb.y; vr[2]+=pa.z*gb.y; vr[3]+=pa.w*gb.y;
      vr[4]+=pb.x*gb.z; vr[5]+=pb.y*gb.z; vr[6]+=pb.z*gb.z; vr[7]+=pb.w*gb.w;
    }
    float g[8];
    #pragma unroll
    for(int b=0;b<8;b++) g[b]=0.f;
    const int MASKS[8]={0,1,2,4,3,5,6,7};
    #pragma unroll
    for(int i=0;i<8;i++){
      #pragma unroll
      for(int jj=0;jj<8;jj++){
        const int a=MASKS[i], b=MASKS[jj];
        const int kk=MASKS[a^b];
        int sg=1;
        for(int tt=a>>1; tt; tt>>=1) if(__popc(tt&b)&1) sg=-sg;
        const float pr = vl[i]*vr[jj];
        g[kk] += (sg>0)? pr : -pr;
      }
    }
    *(float4*)(sG + n*128 + o*8)     = make_float4(g[0],g[1],g[2],g[3]);
    *(float4*)(sG + n*128 + o*8 + 4) = make_float4(g[4],g[5],g[6],g[7]);
  }
  __syncthreads();
  {
    const int n = t>>4, o = t&15;
    #pragma unroll
    for(int b=0;b<8;b++) vo[b]=0.f;
    vo[0]=gob[o];
    #pragma unroll
    for(int c=0;c<32;c++){
      const float* src = (c<16) ? (sG + n*128 + c*8) : (sP + n*128 + (c-16)*8);
      float4 sa=*(const float4*)(src);
      float4 sb=*(const float4*)(src+4);
      float4 gw=*(const float4*)(gow + (o*32+c)*4);
      vo[0]+=sa.x*gw.x; vo[1]+=sa.y*gw.y; vo[2]+=sa.z*gw.y; vo[3]+=sa.w*gw.y;
      vo[4]+=sb.x*gw.z; vo[5]+=sb.y*gw.z; vo[6]+=sb.z*gw.z; vo[7]+=sb.w*gw.w;
    }
    float ssum=0.f;
    #pragma unroll
    for(int b=0;b<8;b++) ssum+=vo[b]*vo[b];
    sNrm[t]=sqrtf(ssum);
  }
  __syncthreads();
  {
    const int n = t>>4, o = t&15;
    float mn=0.f;
    #pragma unroll
    for(int c=0;c<16;c++) mn += sNrm[n*16+c];
    mn = mn*(1.f/16.f) + 1e-6f;
    const float sc = lna[o]/mn;
    const size_t base = (size_t)(nb+n)*128 + o*8;
    float4 v0=*(const float4*)(v+base);
    float4 v1=*(const float4*)(v+base+4);
    *(float4*)(outV+base)   = make_float4(vo[0]*sc+v0.x, vo[1]*sc+v0.y, vo[2]*sc+v0.z, vo[3]*sc+v0.w);
    *(float4*)(outV+base+4) = make_float4(vo[4]*sc+v1.x, vo[5]*sc+v1.y, vo[6]*sc+v1.z, vo[7]*sc+v1.w);
  }
}

extern "C" void kernel_launch(void* const* d_in, const int* in_sizes, int n_in,
                              void* d_out, int out_size, void* d_ws, size_t ws_size,
                              hipStream_t stream){
  (void)in_sizes; (void)n_in; (void)out_size;
  const float* s    = (const float*)d_in[0];
  const float* v    = (const float*)d_in[1];
  const int*   eidx = (const int*)d_in[2];
  const float* Wvw  = (const float*)d_in[3];
  const float* Wvb  = (const float*)d_in[4];
  const float* mnW1 = (const float*)d_in[5];
  const float* mnb1 = (const float*)d_in[6];
  const float* mnW2 = (const float*)d_in[7];
  const float* mnb2 = (const float*)d_in[8];
  const float* pnW1 = (const float*)d_in[9];
  const float* pnb1 = (const float*)d_in[10];
  const float* pnW2 = (const float*)d_in[11];
  const float* pnb2 = (const float*)d_in[12];
  const float* unW1 = (const float*)d_in[13];
  const float* unb1 = (const float*)d_in[14];
  const float* unW2 = (const float*)d_in[15];
  const float* unb2 = (const float*)d_in[16];
  const float* glw  = (const float*)d_in[17];
  const float* glb  = (const float*)d_in[18];
  const float* grw  = (const float*)d_in[19];
  const float* grb  = (const float*)d_in[20];
  const float* gow  = (const float*)d_in[21];
  const float* gob  = (const float*)d_in[22];
  const float* lna  = (const float*)d_in[23];

  float* outS = (float*)d_out;
  float* outV = outS + (size_t)NN*128;
  float* A    = outS;            // A/Bn stage in d_out (dead until k_node writes)
  float* Bn   = outV;

  float* Magg = (float*)d_ws;
  float* Pagg = Magg + (size_t)NN*128;
  int* degS = (int*)(Pagg + (size_t)NN*128);
  int* cntR = degS + NN;
  int* cur  = cntR + NN;
  int* eord = cur + NN;
  _Float16* W2h  = (_Float16*)(eord + NE);
  _Float16* pW1h = W2h + 16384;

  const size_t need = ((size_t)2*NN*128)*sizeof(float) + ((size_t)3*NN + NE)*sizeof(int)
                    + (size_t)2*16384*sizeof(_Float16);

  if(ws_size >= need){
    (void)hipMemsetAsync(Magg, 0, (size_t)2*NN*128*sizeof(float) + (size_t)2*NN*sizeof(int), stream);
    k_prep<<<64, 256, 0, stream>>>(mnW2, pnW1, W2h, pW1h);
    k_hist<<<(NE+255)/256, 256, 0, stream>>>(eidx, degS, cntR, 1);
    k_scan<<<1, 256, 0, stream>>>(cntR, cur);
    k_fill<<<(NE+255)/256, 256, 0, stream>>>(eidx, cur, eord);
    k_ab<<<NN/8, 256, 0, stream>>>(s, mnW1, A, Bn);
    k_edgeM<<<NE/ET, 256, 0, stream>>>(v, eidx, Wvw, Wvb, mnW1 + 256*128, mnb1,
                                       mnb2, pnb1, pnW2, pnb2,
                                       A, Bn, eord, W2h, pW1h, Magg, Pagg);
    k_node<<<NN/16, 256, 0, stream>>>(s, v, unW1, unb1, unW2, unb2,
                                      glw, glb, grw, grb, gow, gob, lna,
                                      Magg, Pagg, degS, outS, outV);
  } else {
    (void)hipMemsetAsync(Magg, 0, (size_t)2*NN*128*sizeof(float) + (size_t)NN*sizeof(int), stream);
    k_hist<<<(NE+255)/256, 256, 0, stream>>>(eidx, degS, (int*)0, 0);
    k_ab<<<NN/8, 256, 0, stream>>>(s, mnW1, A, Bn);
    k_edge0<<<NE/ET, 256, 0, stream>>>(v, eidx, Wvw, Wvb, mnW1 + 256*128, mnb1,
                                       mnW2, mnb2, pnW1, pnb1, pnW2, pnb2,
                                       A, Bn, Magg, Pagg);
    k_node<<<NN/16, 256, 0, stream>>>(s, v, unW1, unb1, unW2, unb2,
                                      glw, glb, grw, grb, gow, gob, lna,
                                      Magg, Pagg, degS, outS, outV);
  }
}